// Round 14
// baseline (449.171 us; speedup 1.0000x reference)
//
#include <hip/hip_runtime.h>
#include <hip/hip_cooperative_groups.h>
#include <math.h>

namespace cg = cooperative_groups;

#define BB 1024
#define NN 4096
#define HH 32
#define GB 2048              // cooperative grid: 2048 blocks = 8/CU x 256 CU
#define HR (NN / 2)          // 2048 rows per half-batch
#define PP 4                 // fallback K1 partial blocks per batch
#define RK1 (NN / PP)

typedef float floatx4 __attribute__((ext_vector_type(4)));

// ws layout (floats)
#define WS_PART 0                        // coop: [BB*2*HH) half partials
#define WS_FB   (BB * 2 * HH)            // fallback: [BB*PP*HH) quarter partials

// ================= cooperative single-dispatch kernel =====================
__global__ __launch_bounds__(256, 8) void fused(
    const float* __restrict__ ne, const float* __restrict__ mask,
    const float* __restrict__ times,
    const float* __restrict__ W1, const float* __restrict__ b1,
    const float* __restrict__ Wq, const float* __restrict__ Wk,
    const int* __restrict__ idxc,
    float* __restrict__ ws, float* __restrict__ out)
{
    __shared__ float smem[NN + 160];
    const int tid = threadIdx.x;
    const int g   = blockIdx.x;
    const int q8  = tid & 7;
    const int r   = tid >> 3;        // 0..31

    // ---- phase 1: half-batch column-sum partials ----
    {
        const int b = g >> 1;
        const int h = g & 1;
        const float* base = ne + (size_t)b * (NN * HH)
                               + (size_t)(h * HR + r) * HH + q8 * 4;
        float a0 = 0.f, a1 = 0.f, a2 = 0.f, a3 = 0.f;
        #pragma unroll 8
        for (int i = 0; i < HR / 32; ++i) {            // 64 iters
            const floatx4 v = __builtin_nontemporal_load(
                reinterpret_cast<const floatx4*>(base + i * (32 * HH)));
            a0 += v.x; a1 += v.y; a2 += v.z; a3 += v.w;
        }
        *reinterpret_cast<float4*>(&smem[tid * 4]) = make_float4(a0, a1, a2, a3);
        __syncthreads();

        if (tid < HH) {     // deterministic fixed-order reduce
            const int q = tid >> 2, j = tid & 3;
            float s = 0.f;
            #pragma unroll
            for (int rr = 0; rr < 32; ++rr) s += smem[(rr * 8 + q) * 4 + j];
            ws[WS_PART + (b * 2 + h) * HH + tid] = s;
        }
    }

    cg::this_grid().sync();

    // ---- phase 2: fused MLP + scores + softmax (blocks < BB) ----
    if (g >= BB) return;
    const int b = g;

    float* s_scores = smem;
    float* sh_avg   = smem + NN;
    float* sh_f     = smem + NN + 32;
    float* sh_emb   = smem + NN + 64;
    float* sh_qk    = smem + NN + 96;
    float* red_buf  = smem + NN + 128;

    if (tid < HH) {
        const float s = ws[WS_PART + (b * 2 + 0) * HH + tid]
                      + ws[WS_PART + (b * 2 + 1) * HH + tid];
        sh_avg[tid] = s * (1.0f / (float)NN);
        sh_f[tid]   = ne[(size_t)b * (NN * HH) + (size_t)idxc[b] * HH + tid];
    }
    __syncthreads();
    if (tid < HH) {
        const float t = times[b];
        const float* w = W1 + tid * (2 * HH + 1);
        float e = b1[tid];
        #pragma unroll
        for (int j = 0; j < HH; ++j) e += sh_avg[j] * w[j];
        #pragma unroll
        for (int j = 0; j < HH; ++j) e += sh_f[j] * w[HH + j];
        e += t * w[2 * HH];
        sh_emb[tid] = e;
    }
    __syncthreads();
    if (tid < HH) {
        const float* w = Wq + tid * HH;
        float qv = 0.f;
        #pragma unroll
        for (int j = 0; j < HH; ++j) qv += sh_emb[j] * w[j];
        sh_f[tid] = qv;
    }
    __syncthreads();
    if (tid < HH) {
        float s = 0.f;
        #pragma unroll
        for (int h = 0; h < HH; ++h) s += sh_f[h] * Wk[h * HH + tid];
        sh_qk[tid] = s * 0.17677669529663687f;
    }
    __syncthreads();

    const float kq0 = sh_qk[q8 * 4 + 0];
    const float kq1 = sh_qk[q8 * 4 + 1];
    const float kq2 = sh_qk[q8 * 4 + 2];
    const float kq3 = sh_qk[q8 * 4 + 3];

    const float* base = ne + (size_t)b * (NN * HH) + (size_t)r * HH + q8 * 4;

    #pragma unroll 8
    for (int i = 0; i < NN / 32; ++i) {               // 128 iters
        const floatx4 v = __builtin_nontemporal_load(
            reinterpret_cast<const floatx4*>(base + i * (32 * HH)));
        float p = v.x * kq0 + v.y * kq1 + v.z * kq2 + v.w * kq3;
        p += __shfl_xor(p, 1);
        p += __shfl_xor(p, 2);
        p += __shfl_xor(p, 4);
        if (q8 == 0) s_scores[r + i * 32] = p;
    }
    __syncthreads();

    const float* mrow = mask + (size_t)b * NN;
    float lmax = -INFINITY;
    #pragma unroll
    for (int k = 0; k < NN / 1024; ++k) {
        const int n4 = tid + k * 256;
        const floatx4 mv = __builtin_nontemporal_load(
            reinterpret_cast<const floatx4*>(mrow + n4 * 4));
        float4 sv = *reinterpret_cast<const float4*>(&s_scores[n4 * 4]);
        sv.x -= mv.x * 999999999.0f;
        sv.y -= mv.y * 999999999.0f;
        sv.z -= mv.z * 999999999.0f;
        sv.w -= mv.w * 999999999.0f;
        *reinterpret_cast<float4*>(&s_scores[n4 * 4]) = sv;
        lmax = fmaxf(lmax, fmaxf(fmaxf(sv.x, sv.y), fmaxf(sv.z, sv.w)));
    }
    #pragma unroll
    for (int m = 1; m < 64; m <<= 1) lmax = fmaxf(lmax, __shfl_xor(lmax, m));
    if ((tid & 63) == 0) red_buf[tid >> 6] = lmax;
    __syncthreads();
    const float bmax = fmaxf(fmaxf(red_buf[0], red_buf[1]),
                             fmaxf(red_buf[2], red_buf[3]));

    float lsum = 0.f;
    #pragma unroll
    for (int k = 0; k < NN / 256; ++k) {
        const int n = tid + k * 256;
        const float e = expf(s_scores[n] - bmax);
        s_scores[n] = e;
        lsum += e;
    }
    #pragma unroll
    for (int m = 1; m < 64; m <<= 1) lsum += __shfl_xor(lsum, m);
    __syncthreads();
    if ((tid & 63) == 0) red_buf[tid >> 6] = lsum;
    __syncthreads();
    const float inv = 1.0f / (red_buf[0] + red_buf[1] + red_buf[2] + red_buf[3]);

    float* orow = out + (size_t)b * NN;
    #pragma unroll
    for (int k = 0; k < NN / 1024; ++k) {
        const int n4 = tid + k * 256;
        const float4 ev = *reinterpret_cast<const float4*>(&s_scores[n4 * 4]);
        floatx4 sv;
        sv.x = ev.x * inv; sv.y = ev.y * inv; sv.z = ev.z * inv; sv.w = ev.w * inv;
        __builtin_nontemporal_store(
            sv, reinterpret_cast<floatx4*>(orow + n4 * 4));
    }
}

// ================= fallback: R12 champion two-dispatch path ===============
__global__ __launch_bounds__(256) void k1_colsum(
    const float* __restrict__ ne, float* __restrict__ ws)
{
    const int blk = blockIdx.x;
    const int b   = blk >> 2;
    const int p   = blk & (PP - 1);
    const int tid = threadIdx.x;
    const int q8  = tid & 7;
    const int r   = tid >> 3;

    __shared__ float s_part[256 * 4];

    const float* base = ne + (size_t)b * (NN * HH)
                           + (size_t)(p * RK1 + r) * HH + q8 * 4;
    float a0 = 0.f, a1 = 0.f, a2 = 0.f, a3 = 0.f;
    #pragma unroll 8
    for (int i = 0; i < RK1 / 32; ++i) {
        const floatx4 v = __builtin_nontemporal_load(
            reinterpret_cast<const floatx4*>(base + i * (32 * HH)));
        a0 += v.x; a1 += v.y; a2 += v.z; a3 += v.w;
    }
    *reinterpret_cast<float4*>(&s_part[tid * 4]) = make_float4(a0, a1, a2, a3);
    __syncthreads();

    if (tid < HH) {
        const int q = tid >> 2, j = tid & 3;
        float s = 0.f;
        #pragma unroll
        for (int rr = 0; rr < 32; ++rr) s += s_part[(rr * 8 + q) * 4 + j];
        ws[WS_FB + (b * PP + p) * HH + tid] = s;
    }
}

__global__ __launch_bounds__(256) void k3_scores(
    const float* __restrict__ ne, const float* __restrict__ mask,
    const float* __restrict__ times,
    const float* __restrict__ W1, const float* __restrict__ b1,
    const float* __restrict__ Wq, const float* __restrict__ Wk,
    const int* __restrict__ idxc,
    const float* __restrict__ ws, float* __restrict__ out)
{
    const int b   = blockIdx.x;
    const int tid = threadIdx.x;
    const int q8  = tid & 7;
    const int r   = tid >> 3;

    __shared__ float s_scores[NN];
    __shared__ float sh_avg[HH], sh_f[HH], sh_emb[HH], sh_qk[HH];
    __shared__ float red_buf[4];

    if (tid < HH) {
        float s = 0.f;
        #pragma unroll
        for (int p = 0; p < PP; ++p) s += ws[WS_FB + (b * PP + p) * HH + tid];
        sh_avg[tid] = s * (1.0f / (float)NN);
        sh_f[tid]   = ne[(size_t)b * (NN * HH) + (size_t)idxc[b] * HH + tid];
    }
    __syncthreads();
    if (tid < HH) {
        const float t = times[b];
        const float* w = W1 + tid * (2 * HH + 1);
        float e = b1[tid];
        #pragma unroll
        for (int j = 0; j < HH; ++j) e += sh_avg[j] * w[j];
        #pragma unroll
        for (int j = 0; j < HH; ++j) e += sh_f[j] * w[HH + j];
        e += t * w[2 * HH];
        sh_emb[tid] = e;
    }
    __syncthreads();
    if (tid < HH) {
        const float* w = Wq + tid * HH;
        float qv = 0.f;
        #pragma unroll
        for (int j = 0; j < HH; ++j) qv += sh_emb[j] * w[j];
        sh_f[tid] = qv;
    }
    __syncthreads();
    if (tid < HH) {
        float s = 0.f;
        #pragma unroll
        for (int h = 0; h < HH; ++h) s += sh_f[h] * Wk[h * HH + tid];
        sh_qk[tid] = s * 0.17677669529663687f;
    }
    __syncthreads();

    const float kq0 = sh_qk[q8 * 4 + 0];
    const float kq1 = sh_qk[q8 * 4 + 1];
    const float kq2 = sh_qk[q8 * 4 + 2];
    const float kq3 = sh_qk[q8 * 4 + 3];

    const float* base = ne + (size_t)b * (NN * HH) + (size_t)r * HH + q8 * 4;

    #pragma unroll 8
    for (int i = 0; i < NN / 32; ++i) {
        const floatx4 v = __builtin_nontemporal_load(
            reinterpret_cast<const floatx4*>(base + i * (32 * HH)));
        float p = v.x * kq0 + v.y * kq1 + v.z * kq2 + v.w * kq3;
        p += __shfl_xor(p, 1);
        p += __shfl_xor(p, 2);
        p += __shfl_xor(p, 4);
        if (q8 == 0) s_scores[r + i * 32] = p;
    }
    __syncthreads();

    const float* mrow = mask + (size_t)b * NN;
    float lmax = -INFINITY;
    #pragma unroll
    for (int k = 0; k < NN / 1024; ++k) {
        const int n4 = tid + k * 256;
        const floatx4 mv = __builtin_nontemporal_load(
            reinterpret_cast<const floatx4*>(mrow + n4 * 4));
        float4 sv = *reinterpret_cast<const float4*>(&s_scores[n4 * 4]);
        sv.x -= mv.x * 999999999.0f;
        sv.y -= mv.y * 999999999.0f;
        sv.z -= mv.z * 999999999.0f;
        sv.w -= mv.w * 999999999.0f;
        *reinterpret_cast<float4*>(&s_scores[n4 * 4]) = sv;
        lmax = fmaxf(lmax, fmaxf(fmaxf(sv.x, sv.y), fmaxf(sv.z, sv.w)));
    }
    #pragma unroll
    for (int m = 1; m < 64; m <<= 1) lmax = fmaxf(lmax, __shfl_xor(lmax, m));
    if ((tid & 63) == 0) red_buf[tid >> 6] = lmax;
    __syncthreads();
    const float bmax = fmaxf(fmaxf(red_buf[0], red_buf[1]),
                             fmaxf(red_buf[2], red_buf[3]));

    float lsum = 0.f;
    #pragma unroll
    for (int k = 0; k < NN / 256; ++k) {
        const int n = tid + k * 256;
        const float e = expf(s_scores[n] - bmax);
        s_scores[n] = e;
        lsum += e;
    }
    #pragma unroll
    for (int m = 1; m < 64; m <<= 1) lsum += __shfl_xor(lsum, m);
    __syncthreads();
    if ((tid & 63) == 0) red_buf[tid >> 6] = lsum;
    __syncthreads();
    const float inv = 1.0f / (red_buf[0] + red_buf[1] + red_buf[2] + red_buf[3]);

    float* orow = out + (size_t)b * NN;
    #pragma unroll
    for (int k = 0; k < NN / 1024; ++k) {
        const int n4 = tid + k * 256;
        const float4 ev = *reinterpret_cast<const float4*>(&s_scores[n4 * 4]);
        floatx4 sv;
        sv.x = ev.x * inv; sv.y = ev.y * inv; sv.z = ev.z * inv; sv.w = ev.w * inv;
        __builtin_nontemporal_store(
            sv, reinterpret_cast<floatx4*>(orow + n4 * 4));
    }
}

extern "C" void kernel_launch(void* const* d_in, const int* in_sizes, int n_in,
                              void* d_out, int out_size, void* d_ws, size_t ws_size,
                              hipStream_t stream) {
    (void)in_sizes; (void)n_in; (void)ws_size; (void)out_size;
    const float* ne    = (const float*)d_in[0];
    const float* mask  = (const float*)d_in[1];
    const float* times = (const float*)d_in[2];
    // d_in[3] = vf, unused (idxc path taken)
    const float* W1    = (const float*)d_in[4];
    const float* b1    = (const float*)d_in[5];
    const float* Wq    = (const float*)d_in[6];
    const float* Wk    = (const float*)d_in[7];
    const int*   idxc  = (const int*)d_in[8];
    float* out = (float*)d_out;
    float* ws  = (float*)d_ws;

    void* args[] = {(void*)&ne, (void*)&mask, (void*)&times, (void*)&W1,
                    (void*)&b1, (void*)&Wq, (void*)&Wk, (void*)&idxc,
                    (void*)&ws, (void*)&out};
    const hipError_t err = hipLaunchCooperativeKernel(
        (const void*)fused, dim3(GB), dim3(256), args, 0, stream);
    if (err != hipSuccess) {
        // deterministic fallback: R12 champion path
        k1_colsum<<<dim3(BB * PP), dim3(256), 0, stream>>>(ne, ws);
        k3_scores<<<dim3(BB), dim3(256), 0, stream>>>(
            ne, mask, times, W1, b1, Wq, Wk, idxc, ws, out);
    }
}

// Round 15
// 183.832 us; speedup vs baseline: 2.4434x; 2.4434x over previous
//
#include <hip/hip_runtime.h>
#include <math.h>

#define BB 1024
#define NN 4096
#define HH 32
#define PP 4                 // K1 partial blocks per batch
#define RK1 (NN / PP)        // 1024 rows per K1 block

typedef float floatx4 __attribute__((ext_vector_type(4)));

// ws layout (floats)
#define WS_PART 0                    // [BB*PP*HH) column-sum partials

// ---------------- K1: per-batch column-sum partials (champion, NT) --------
__global__ __launch_bounds__(256) void k1_colsum(
    const float* __restrict__ ne, float* __restrict__ ws)
{
    const int blk = blockIdx.x;
    const int b   = blk >> 2;
    const int p   = blk & (PP - 1);
    const int tid = threadIdx.x;
    const int q8  = tid & 7;     // float4 chunk within row
    const int r   = tid >> 3;    // row offset 0..31

    __shared__ float s_part[256 * 4];

    const float* base = ne + (size_t)b * (NN * HH)
                           + (size_t)(p * RK1 + r) * HH + q8 * 4;
    float a0 = 0.f, a1 = 0.f, a2 = 0.f, a3 = 0.f;
    #pragma unroll 8
    for (int i = 0; i < RK1 / 32; ++i) {               // 32 iters
        const floatx4 v = __builtin_nontemporal_load(
            reinterpret_cast<const floatx4*>(base + i * (32 * HH)));
        a0 += v.x; a1 += v.y; a2 += v.z; a3 += v.w;
    }
    *reinterpret_cast<float4*>(&s_part[tid * 4]) = make_float4(a0, a1, a2, a3);
    __syncthreads();

    // deterministic fixed-order reduce: thread h sums its column's 32 partials
    if (tid < HH) {
        const int q = tid >> 2, j = tid & 3;
        float s = 0.f;
        #pragma unroll
        for (int rr = 0; rr < 32; ++rr) s += s_part[(rr * 8 + q) * 4 + j];
        ws[WS_PART + (b * PP + p) * HH + tid] = s;
    }
}

// ---------------- K3: fused MLP prelude + scores + softmax (NT) -----------
// grid = BB blocks x 256 thr, LDS 16.6 KB -> 8 blocks/CU resident.
__global__ __launch_bounds__(256) void k3_scores(
    const float* __restrict__ ne, const float* __restrict__ mask,
    const float* __restrict__ times,
    const float* __restrict__ W1, const float* __restrict__ b1,
    const float* __restrict__ Wq, const float* __restrict__ Wk,
    const int* __restrict__ idxc,
    const float* __restrict__ ws, float* __restrict__ out)
{
    const int b   = blockIdx.x;
    const int tid = threadIdx.x;
    const int q8  = tid & 7;
    const int r   = tid >> 3;    // 0..31

    __shared__ float s_scores[NN];     // 16 KB
    __shared__ float sh_avg[HH], sh_f[HH], sh_emb[HH], sh_qk[HH];
    __shared__ float red_buf[4];

    // ---- prelude: rebuild avg from partials, gather f, tiny MLP -> qk ----
    if (tid < HH) {
        float s = 0.f;
        #pragma unroll
        for (int p = 0; p < PP; ++p) s += ws[WS_PART + (b * PP + p) * HH + tid];
        sh_avg[tid] = s * (1.0f / (float)NN);
        sh_f[tid]   = ne[(size_t)b * (NN * HH) + (size_t)idxc[b] * HH + tid];
    }
    __syncthreads();
    if (tid < HH) {
        const float t = times[b];
        const float* w = W1 + tid * (2 * HH + 1);
        float e = b1[tid];
        #pragma unroll
        for (int j = 0; j < HH; ++j) e += sh_avg[j] * w[j];
        #pragma unroll
        for (int j = 0; j < HH; ++j) e += sh_f[j] * w[HH + j];
        e += t * w[2 * HH];
        sh_emb[tid] = e;
    }
    __syncthreads();
    if (tid < HH) {  // q = emb @ Wq^T (reuse sh_f)
        const float* w = Wq + tid * HH;
        float qv = 0.f;
        #pragma unroll
        for (int j = 0; j < HH; ++j) qv += sh_emb[j] * w[j];
        sh_f[tid] = qv;
    }
    __syncthreads();
    if (tid < HH) {  // qk[j] = sum_h q[h]*Wk[h,j], scaled 1/sqrt(H)
        float s = 0.f;
        #pragma unroll
        for (int h = 0; h < HH; ++h) s += sh_f[h] * Wk[h * HH + tid];
        sh_qk[tid] = s * 0.17677669529663687f;
    }
    __syncthreads();

    const float kq0 = sh_qk[q8 * 4 + 0];
    const float kq1 = sh_qk[q8 * 4 + 1];
    const float kq2 = sh_qk[q8 * 4 + 2];
    const float kq3 = sh_qk[q8 * 4 + 3];

    const float* base = ne + (size_t)b * (NN * HH) + (size_t)r * HH + q8 * 4;

    // ---- raw dot products into LDS (single-use stream -> NT loads) ----
    #pragma unroll 8
    for (int i = 0; i < NN / 32; ++i) {               // 128 iters
        const floatx4 v = __builtin_nontemporal_load(
            reinterpret_cast<const floatx4*>(base + i * (32 * HH)));
        float p = v.x * kq0 + v.y * kq1 + v.z * kq2 + v.w * kq3;
        p += __shfl_xor(p, 1);
        p += __shfl_xor(p, 2);
        p += __shfl_xor(p, 4);
        if (q8 == 0) s_scores[r + i * 32] = p;
    }
    __syncthreads();

    // ---- apply mask (coalesced NT float4), block max ----
    const float* mrow = mask + (size_t)b * NN;
    float lmax = -INFINITY;
    #pragma unroll
    for (int k = 0; k < NN / 1024; ++k) {             // 4 iters, float4 each
        const int n4 = tid + k * 256;                 // float4 index
        const floatx4 mv = __builtin_nontemporal_load(
            reinterpret_cast<const floatx4*>(mrow + n4 * 4));
        float4 sv = *reinterpret_cast<const float4*>(&s_scores[n4 * 4]);
        sv.x -= mv.x * 999999999.0f;
        sv.y -= mv.y * 999999999.0f;
        sv.z -= mv.z * 999999999.0f;
        sv.w -= mv.w * 999999999.0f;
        *reinterpret_cast<float4*>(&s_scores[n4 * 4]) = sv;
        lmax = fmaxf(lmax, fmaxf(fmaxf(sv.x, sv.y), fmaxf(sv.z, sv.w)));
    }
    #pragma unroll
    for (int m = 1; m < 64; m <<= 1) lmax = fmaxf(lmax, __shfl_xor(lmax, m));
    if ((tid & 63) == 0) red_buf[tid >> 6] = lmax;
    __syncthreads();
    const float bmax = fmaxf(fmaxf(red_buf[0], red_buf[1]),
                             fmaxf(red_buf[2], red_buf[3]));

    // ---- exp + sum ----
    float lsum = 0.f;
    #pragma unroll
    for (int k = 0; k < NN / 256; ++k) {
        const int n = tid + k * 256;
        const float e = expf(s_scores[n] - bmax);
        s_scores[n] = e;
        lsum += e;
    }
    #pragma unroll
    for (int m = 1; m < 64; m <<= 1) lsum += __shfl_xor(lsum, m);
    __syncthreads();                       // red_buf (max) reads done
    if ((tid & 63) == 0) red_buf[tid >> 6] = lsum;
    __syncthreads();
    const float inv = 1.0f / (red_buf[0] + red_buf[1] + red_buf[2] + red_buf[3]);

    float* orow = out + (size_t)b * NN;
    #pragma unroll
    for (int k = 0; k < NN / 1024; ++k) {             // float4 NT stores
        const int n4 = tid + k * 256;
        const float4 ev = *reinterpret_cast<const float4*>(&s_scores[n4 * 4]);
        floatx4 sv;
        sv.x = ev.x * inv; sv.y = ev.y * inv; sv.z = ev.z * inv; sv.w = ev.w * inv;
        __builtin_nontemporal_store(
            sv, reinterpret_cast<floatx4*>(orow + n4 * 4));
    }
}

extern "C" void kernel_launch(void* const* d_in, const int* in_sizes, int n_in,
                              void* d_out, int out_size, void* d_ws, size_t ws_size,
                              hipStream_t stream) {
    (void)in_sizes; (void)n_in; (void)ws_size; (void)out_size;
    const float* ne    = (const float*)d_in[0];
    const float* mask  = (const float*)d_in[1];
    const float* times = (const float*)d_in[2];
    // d_in[3] = vf, unused (idxc path taken)
    const float* W1    = (const float*)d_in[4];
    const float* b1    = (const float*)d_in[5];
    const float* Wq    = (const float*)d_in[6];
    const float* Wk    = (const float*)d_in[7];
    const int*   idxc  = (const int*)d_in[8];
    float* out = (float*)d_out;
    float* ws  = (float*)d_ws;

    k1_colsum<<<dim3(BB * PP), dim3(256), 0, stream>>>(ne, ws);
    k3_scores<<<dim3(BB), dim3(256), 0, stream>>>(
        ne, mask, times, W1, b1, Wq, Wk, idxc, ws, out);
}